// Round 1
// baseline (397.163 us; speedup 1.0000x reference)
//
#include <hip/hip_runtime.h>
#include <stdint.h>

typedef __attribute__((ext_vector_type(8))) short short8;
typedef __attribute__((ext_vector_type(4))) short short4v;
typedef __attribute__((ext_vector_type(4))) float f32x4;

#define MFMA(a,b,c) __builtin_amdgcn_mfma_f32_16x16x32_bf16((a),(b),(c),0,0,0)

__device__ __forceinline__ unsigned short f2bf(float f) {
    unsigned int u = __float_as_uint(f);
    u += 0x7fffu + ((u >> 16) & 1u);   // round-to-nearest-even
    return (unsigned short)(u >> 16);
}

// ---------------- conversions ----------------
__global__ __launch_bounds__(256) void cvt_f32_bf16(const float* __restrict__ in,
                                                    unsigned short* __restrict__ out, int n4) {
    int i = blockIdx.x * 256 + threadIdx.x;
    if (i < n4) {
        float4 v = ((const float4*)in)[i];
        short4v s;
        s[0] = (short)f2bf(v.x); s[1] = (short)f2bf(v.y);
        s[2] = (short)f2bf(v.z); s[3] = (short)f2bf(v.w);
        ((short4v*)out)[i] = s;
    }
}

// in [R][C] f32 -> out [C][R] bf16   (R,C multiples of 32)
__global__ __launch_bounds__(256) void transpose_cvt(const float* __restrict__ in,
                                                     unsigned short* __restrict__ out,
                                                     int R, int C) {
    __shared__ float tile[32][33];
    int c0 = blockIdx.x * 32, r0 = blockIdx.y * 32;
    int lc = threadIdx.x & 31, lr = threadIdx.x >> 5;     // lr 0..7
    #pragma unroll
    for (int i = 0; i < 4; ++i) {
        int r = lr + i * 8;
        tile[r][lc] = in[(size_t)(r0 + r) * C + c0 + lc];
    }
    __syncthreads();
    #pragma unroll
    for (int i = 0; i < 4; ++i) {
        int r = lr + i * 8;                                // output row = original col
        out[(size_t)(c0 + r) * R + r0 + lc] = f2bf(tile[lc][r]);
    }
}

// ---------------- GEMM: C = A[M,K] * Bt[N,K]^T + bias ----------------
// EPI 0: scatter into Q/K [B,H,577,64] bf16 and Vt [B,H,64,584] bf16
// EPI 1: write fp32 d_out [M,768]
#define VT_LD 584

template<int EPI>
__global__ __launch_bounds__(256) void gemm64(
    const unsigned short* __restrict__ A,
    const unsigned short* __restrict__ Bt,
    const float* __restrict__ bias,
    unsigned short* __restrict__ q_out, unsigned short* __restrict__ k_out,
    unsigned short* __restrict__ vt_out, float* __restrict__ f_out,
    int M, int K)
{
    __shared__ __align__(16) unsigned short As[64][72];
    __shared__ __align__(16) unsigned short Bs[64][72];
    const int t = threadIdx.x;
    const int lane = t & 63, w = t >> 6;
    const int g = lane >> 4, c = lane & 15;
    const int wr = w >> 1, wc = w & 1;
    const int m0 = blockIdx.y * 64, n0 = blockIdx.x * 64;

    f32x4 acc[2][2] = {};
    const int arow = t >> 3;          // 0..31 (per 32-row chunk)
    const int acol = (t & 7) * 8;

    for (int k0 = 0; k0 < K; k0 += 64) {
        #pragma unroll
        for (int ch = 0; ch < 2; ++ch) {
            int row = ch * 32 + arow;
            int ra = m0 + row; ra = ra < M ? ra : M - 1;
            uint4 va = *(const uint4*)&A[(size_t)ra * K + k0 + acol];
            *(uint4*)&As[row][acol] = va;
            uint4 vb = *(const uint4*)&Bt[(size_t)(n0 + row) * K + k0 + acol];
            *(uint4*)&Bs[row][acol] = vb;
        }
        __syncthreads();
        #pragma unroll
        for (int kk = 0; kk < 2; ++kk) {
            short8 a0 = *(const short8*)&As[wr * 32 +      c][kk * 32 + g * 8];
            short8 a1 = *(const short8*)&As[wr * 32 + 16 + c][kk * 32 + g * 8];
            short8 b0 = *(const short8*)&Bs[wc * 32 +      c][kk * 32 + g * 8];
            short8 b1 = *(const short8*)&Bs[wc * 32 + 16 + c][kk * 32 + g * 8];
            acc[0][0] = MFMA(a0, b0, acc[0][0]);
            acc[0][1] = MFMA(a0, b1, acc[0][1]);
            acc[1][0] = MFMA(a1, b0, acc[1][0]);
            acc[1][1] = MFMA(a1, b1, acc[1][1]);
        }
        __syncthreads();
    }

    #pragma unroll
    for (int mf = 0; mf < 2; ++mf)
    #pragma unroll
    for (int nf = 0; nf < 2; ++nf) {
        int n = n0 + wc * 32 + nf * 16 + c;
        float bv = bias[n];
        #pragma unroll
        for (int e = 0; e < 4; ++e) {
            int m = m0 + wr * 32 + mf * 16 + g * 4 + e;
            if (m >= M) continue;
            float v = acc[mf][nf][e] + bv;
            if (EPI == 0) {
                int which = n / 768;
                int r = n - which * 768;
                int h = r >> 6, d = r & 63;
                int b = m / 577, tok = m - b * 577;
                int bh = b * 12 + h;
                unsigned short bv16 = f2bf(v);
                if (which == 0)      q_out[((size_t)bh * 577 + tok) * 64 + d] = bv16;
                else if (which == 1) k_out[((size_t)bh * 577 + tok) * 64 + d] = bv16;
                else                 vt_out[((size_t)bh * 64 + d) * VT_LD + tok] = bv16;
            } else {
                f_out[(size_t)m * 768 + n] = v;
            }
        }
    }
}

// ---------------- flash attention ----------------
// Q,K: [B*H][577][64] bf16 ; Vt: [B*H][64][584] bf16 ; O: [B*577][768] bf16
#define NTOK 577
__global__ __launch_bounds__(256) void attn_flash(
    const unsigned short* __restrict__ Qg,
    const unsigned short* __restrict__ Kg,
    const unsigned short* __restrict__ Vtg,
    unsigned short* __restrict__ Og)
{
    __shared__ __align__(16) unsigned short pt[4][16][72];
    const int qt = blockIdx.x;      // 0..9
    const int bh = blockIdx.y;      // 0..383
    const int b = bh / 12, h = bh - b * 12;
    const int t = threadIdx.x, w = t >> 6, lane = t & 63;
    const int g = lane >> 4, c = lane & 15;

    const unsigned short* Qh = Qg + (size_t)bh * NTOK * 64;
    const unsigned short* Kh = Kg + (size_t)bh * NTOK * 64;
    const unsigned short* Vh = Vtg + (size_t)bh * 64 * VT_LD;

    const int q = qt * 64 + w * 16 + c;          // this lane's query (column of S^T)
    const int qc = q < NTOK ? q : NTOK - 1;

    short8 bq[2];
    bq[0] = *(const short8*)&Qh[(size_t)qc * 64 +      g * 8];
    bq[1] = *(const short8*)&Qh[(size_t)qc * 64 + 32 + g * 8];

    float mrun = -1e30f, lsum = 0.f;
    f32x4 ot[4] = {};

    for (int kt = 0; kt < 10; ++kt) {
        const int kbase = kt * 64;
        // S^T = K * Q^T : rows = keys, cols = q
        f32x4 st[4];
        #pragma unroll
        for (int f = 0; f < 4; ++f) {
            int key = kbase + f * 16 + c;
            int keyc = key < NTOK ? key : NTOK - 1;
            short8 ak0 = *(const short8*)&Kh[(size_t)keyc * 64 +      g * 8];
            short8 ak1 = *(const short8*)&Kh[(size_t)keyc * 64 + 32 + g * 8];
            f32x4 z = {};
            z = MFMA(ak0, bq[0], z);
            z = MFMA(ak1, bq[1], z);
            st[f] = z;
        }
        // scale + mask + tile max (row r = 4g+e within frag f -> key)
        float s[4][4];
        float tmax = -1e30f;
        #pragma unroll
        for (int f = 0; f < 4; ++f)
        #pragma unroll
        for (int e = 0; e < 4; ++e) {
            int key = kbase + f * 16 + g * 4 + e;
            float v = st[f][e] * 0.125f;
            v = key < NTOK ? v : -1e30f;
            s[f][e] = v;
            tmax = fmaxf(tmax, v);
        }
        tmax = fmaxf(tmax, __shfl_xor(tmax, 16));
        tmax = fmaxf(tmax, __shfl_xor(tmax, 32));
        float mnew = fmaxf(mrun, tmax);
        float alpha = exp2f((mrun - mnew) * 1.4426950408889634f);
        mrun = mnew;
        lsum *= alpha;
        #pragma unroll
        for (int df = 0; df < 4; ++df) {
            ot[df][0] *= alpha; ot[df][1] *= alpha;
            ot[df][2] *= alpha; ot[df][3] *= alpha;
        }
        // P = exp(S - m), stash P^T per wave: pt[w][q][key_in_tile]
        #pragma unroll
        for (int f = 0; f < 4; ++f) {
            short4v pv;
            #pragma unroll
            for (int e = 0; e < 4; ++e) {
                float p = exp2f((s[f][e] - mrun) * 1.4426950408889634f);
                lsum += p;
                pv[e] = (short)f2bf(p);
            }
            *(short4v*)&pt[w][c][f * 16 + g * 4] = pv;
        }
        asm volatile("s_waitcnt lgkmcnt(0)" ::: "memory");
        // O^T += V^T * P
        #pragma unroll
        for (int kk = 0; kk < 2; ++kk) {
            int kb = kbase + kk * 32 + g * 8;
            if (kb > NTOK - 1) kb = NTOK - 1 - 0;   // clamp; clamped slots have P=0
            if (kb > 576) kb = 576;
            short8 bp = *(const short8*)&pt[w][c][kk * 32 + g * 8];
            #pragma unroll
            for (int df = 0; df < 4; ++df) {
                short8 av = *(const short8*)&Vh[(size_t)(df * 16 + c) * VT_LD + kb];
                ot[df] = MFMA(av, bp, ot[df]);
            }
        }
    }
    lsum += __shfl_xor(lsum, 16);
    lsum += __shfl_xor(lsum, 32);
    float inv = 1.0f / lsum;
    if (q < NTOK) {
        size_t orow = ((size_t)b * NTOK + q) * 768 + h * 64;
        #pragma unroll
        for (int df = 0; df < 4; ++df) {
            short4v ov;
            ov[0] = (short)f2bf(ot[df][0] * inv);
            ov[1] = (short)f2bf(ot[df][1] * inv);
            ov[2] = (short)f2bf(ot[df][2] * inv);
            ov[3] = (short)f2bf(ot[df][3] * inv);
            *(short4v*)&Og[orow + df * 16 + g * 4] = ov;
        }
    }
}

// ---------------- launch ----------------
extern "C" void kernel_launch(void* const* d_in, const int* in_sizes, int n_in,
                              void* d_out, int out_size, void* d_ws, size_t ws_size,
                              hipStream_t stream) {
    const float* x      = (const float*)d_in[0];
    const float* W_qkv  = (const float*)d_in[1];
    const float* b_qkv  = (const float*)d_in[2];
    const float* W_proj = (const float*)d_in[3];
    const float* b_proj = (const float*)d_in[4];
    float* out = (float*)d_out;

    const int B = 32, N = 577, C = 768, H = 12;
    const int M = B * N;            // 18464

    char* ws = (char*)d_ws;
    size_t off = 0;
    auto alloc = [&](size_t bytes) {
        char* p = ws + off;
        off += (bytes + 255) & ~(size_t)255;
        return p;
    };
    unsigned short* xb    = (unsigned short*)alloc((size_t)M * C * 2);       // aliased by attn_out later
    unsigned short* wqkvt = (unsigned short*)alloc((size_t)3 * C * C * 2);
    unsigned short* wprjt = (unsigned short*)alloc((size_t)C * C * 2);
    unsigned short* Qb    = (unsigned short*)alloc((size_t)B * H * N * 64 * 2);
    unsigned short* Kb    = (unsigned short*)alloc((size_t)B * H * N * 64 * 2);
    unsigned short* Vtb   = (unsigned short*)alloc((size_t)B * H * 64 * VT_LD * 2);
    unsigned short* attn  = xb;     // x_bf16 dead after QKV GEMM

    int n4 = M * C / 4;
    cvt_f32_bf16<<<dim3((n4 + 255) / 256), 256, 0, stream>>>(x, xb, n4);
    transpose_cvt<<<dim3(3 * C / 32, C / 32), 256, 0, stream>>>(W_qkv, wqkvt, C, 3 * C);
    transpose_cvt<<<dim3(C / 32, C / 32), 256, 0, stream>>>(W_proj, wprjt, C, C);

    gemm64<0><<<dim3(3 * C / 64, (M + 63) / 64), 256, 0, stream>>>(
        xb, wqkvt, b_qkv, Qb, Kb, Vtb, nullptr, M, C);

    attn_flash<<<dim3(10, B * H), 256, 0, stream>>>(Qb, Kb, Vtb, attn);

    gemm64<1><<<dim3(C / 64, (M + 63) / 64), 256, 0, stream>>>(
        attn, wprjt, b_proj, nullptr, nullptr, nullptr, out, M, C);
}